// Round 21
// baseline (40.224 us; speedup 1.0000x reference)
//
#include <hip/hip_runtime.h>
#include <hip/hip_fp16.h>
#include <stdint.h>
#include <math.h>

#define BS    2
#define RAYS  514
#define NS    64
#define LSEQ  512
#define NF    257
#define HIDN  64
#define SPLIT 4
#define JC    16      // hidden columns per k2 block

#define TWO_PI_F 6.28318530717958647692f

__device__ __forceinline__ uint32_t rotl32(uint32_t x, int d){ return (x<<d)|(x>>(32-d)); }

__device__ __forceinline__ void tf_rounds4(uint32_t& x0, uint32_t& x1, int a, int b, int c, int d){
  x0+=x1; x1=rotl32(x1,a); x1^=x0;
  x0+=x1; x1=rotl32(x1,b); x1^=x0;
  x0+=x1; x1=rotl32(x1,c); x1^=x0;
  x0+=x1; x1=rotl32(x1,d); x1^=x0;
}

// Threefry-2x32, 20 rounds, matching jax._src.prng.threefry2x32
__device__ void threefry2x32(uint32_t k0, uint32_t k1, uint32_t x0, uint32_t x1,
                             uint32_t& o0, uint32_t& o1)
{
  const uint32_t ks2 = k0 ^ k1 ^ 0x1BD11BDAu;
  x0 += k0; x1 += k1;
  tf_rounds4(x0,x1,13,15,26,6);   x0+=k1;  x1+=ks2+1u;
  tf_rounds4(x0,x1,17,29,16,24);  x0+=ks2; x1+=k0+2u;
  tf_rounds4(x0,x1,13,15,26,6);   x0+=k0;  x1+=k1+3u;
  tf_rounds4(x0,x1,17,29,16,24);  x0+=k1;  x1+=ks2+4u;
  tf_rounds4(x0,x1,13,15,26,6);   x0+=ks2; x1+=k0+5u;
  o0 = x0; o1 = x1;
}

// Reproduces _ray_directions() for ray r (verified round 0).
__device__ void ray_dir(int r, float d[3])
{
  if (r >= 512) { d[0]=0.f; d[1]=0.f; d[2] = (r==512) ? 1.0f : -1.0f; return; }
  int i = r >> 4, j = r & 15;
  uint32_t o0, o1;
  threefry2x32(0u, 42u, 0u, (uint32_t)i, o0, o1);
  uint32_t bits = o0 ^ o1;
  float u = __uint_as_float((bits >> 9) | 0x3F800000u) - 1.0f;   // uniform [0,1)
  const float step = TWO_PI_F / 32.0f;
  float a = (float)i * step + step * u;
  float e = acosf(2.0f * ((float)(j+1) * (1.0f/17.0f)) - 1.0f);
  float se = sinf(e);
  d[0] = cosf(a) * se;
  d[1] = sinf(a) * se;
  d[2] = cosf(e);
}

__device__ __forceinline__ float dval(int s){ return ((float)s*(1.0f/63.0f))*7.9f + 0.1f; }

__device__ __forceinline__ uint32_t pk2(float a, float b){
  return (uint32_t)__half_as_ushort(__float2half(a)) |
         ((uint32_t)__half_as_ushort(__float2half(b)) << 16);
}

// K1 v4: 1024 threads = 16 waves = 4 rays x 4 j-quarter waves. Wave (rl,jv)
// computes h[jv*16 .. jv*16+16) for ray rl (= wh quarter p=jv). 4x TLP
// (4 waves/SIMD vs 1) + 4x shorter per-wave chains; shared PRNG/feat/scan
// duplicated across jv (fills idle issue slots). av via one LDS exchange.
// R20's LDS-tile + 128-B cooperative writeout retained verbatim.
__global__ __launch_bounds__(1024)
void k1_rays(const float* __restrict__ rays_o, const float* __restrict__ position_tx,
             const float* __restrict__ W1, const float* __restrict__ b1,
             const float* __restrict__ w_attn,
             __half* __restrict__ wh, float* __restrict__ w_arr, int* __restrict__ delay_arr,
             float* __restrict__ out)
{
  __shared__ uint4 tile[8][4][64];   // [p*2+half][r_local][s] = 32,768 B
  __shared__ float avs[4][4][64];    // [r_local][jv][s] = 4,096 B
  const int tid = threadIdx.x;
  const int wv = tid >> 6, lane = tid & 63;        // lane = s index
  const int rl = wv >> 2, jv = wv & 3;             // ray-local, j-quarter
  const int br = blockIdx.x*4 + rl;                // 257*4 = 1028 = BS*RAYS
  const int b = br / RAYS, r = br % RAYS;

  { // zero the atomic output accumulator
    int gi = blockIdx.x*1024 + tid;
    if (gi < BS*NF*2) out[gi] = 0.f;
  }

  float dir[3]; ray_dir(r, dir);
  const float mn[3] = {-5.f,-5.f,-3.f}, mx[3] = {5.f,5.f,3.f};
  float ro[3], ntx[3];
  #pragma unroll
  for (int c=0;c<3;c++){
    ro[c] = rays_o[b*3+c];
    float t = position_tx[b*3+c];
    ntx[c] = 2.0f*(t - mn[c])/(mx[c]-mn[c]) - 1.0f;
  }

  const float dv = dval(lane);
  float feat[9], dd2 = 0.f;
  #pragma unroll
  for (int c=0;c<3;c++){
    float pt = ro[c] + dir[c]*dv;
    float npt = 2.0f*(pt - mn[c])/(mx[c]-mn[c]) - 1.0f;
    float ddc = ((ntx[c]-npt) + 1.0f)/2.0f*(mx[c]-mn[c]) + mn[c];
    dd2 += ddc*ddc;
    feat[c]   = npt;
    feat[3+c] = -dir[c];
    feat[6+c] = ntx[c];
  }

  // this wave's 16 hidden columns (j = jv*16 + jj)
  float h[16];
  float avp = 0.f;
  const int jb = jv*16;
  #pragma unroll
  for (int jj=0; jj<16; jj++){
    const int j = jb + jj;
    float hj = b1[j];
    #pragma unroll
    for (int f=0; f<9; f++) hj = fmaf(feat[f], W1[f*HIDN + j], hj);
    hj = fmaxf(hj, 0.0f);
    h[jj] = hj;
    avp = fmaf(hj, w_attn[j], avp);
  }
  avs[rl][jv][lane] = avp;
  __syncthreads();
  float av = avs[rl][0][lane] + avs[rl][1][lane] + avs[rl][2][lane] + avs[rl][3][lane];

  float attn = fmaxf(av, 0.f) + log1pf(expf(-fabsf(av)));   // softplus
  float dist = (lane < NS-1) ? (dval(lane+1) - dv) : 1e10f;
  float alpha = 1.0f - expf(-attn*dist);

  // inclusive multiplicative scan of (1-alpha+1e-6), shifted -> transmittance
  // (computed redundantly by the 4 jv-waves of this ray — identical values)
  float fac = 1.0f - alpha + 1e-6f;
  float scan = fac;
  #pragma unroll
  for (int m=1; m<64; m<<=1){
    float up = __shfl_up(scan, m, 64);
    if (lane >= m) scan *= up;
  }
  float T = __shfl_up(scan, 1, 64);
  if (lane == 0) T = 1.0f;
  float wgt = T * alpha;

  const int bsid = b*NS + lane;
  const int o2 = bsid*RAYS + r;
  if (jv == 0){
    float delf = fminf(fmaxf(rintf(sqrtf(dd2)*16000.0f/343.0f), 0.f), 511.f);
    w_arr[o2] = wgt;
    delay_arr[o2] = (int)delf;
  }

  // stage this wave's quarter (p = jv) into the LDS tile
  {
    uint4 v0, v1;
    v0.x = pk2(wgt*h[ 0], wgt*h[ 1]);
    v0.y = pk2(wgt*h[ 2], wgt*h[ 3]);
    v0.z = pk2(wgt*h[ 4], wgt*h[ 5]);
    v0.w = pk2(wgt*h[ 6], wgt*h[ 7]);
    v1.x = pk2(wgt*h[ 8], wgt*h[ 9]);
    v1.y = pk2(wgt*h[10], wgt*h[11]);
    v1.z = pk2(wgt*h[12], wgt*h[13]);
    v1.w = pk2(wgt*h[14], wgt*h[15]);
    tile[jv*2+0][rl][lane] = v0;
    tile[jv*2+1][rl][lane] = v1;
  }
  __syncthreads();

  // cooperative write-out: 2048 uint4s in 2 sweeps; 8 consecutive tids cover
  // one contiguous 128-B destination chunk (4 r_local x 2 half, fixed (p,s)).
  uint4* wh4 = (uint4*)wh;
  #pragma unroll
  for (int i=0; i<2; i++){
    int g = i*1024 + tid;
    int slot = g & 7, s = (g >> 3) & 63, p = g >> 9;
    int rrl = slot >> 1, half = slot & 1;
    int brl = blockIdx.x*4 + rrl;
    int bb = brl / RAYS, rr = brl - bb*RAYS;
    size_t idx4 = (((size_t)p*BS*NS + bb*NS + s)*RAYS + rr)*2 + half;
    wh4[idx4] = tile[p*2+half][rrl][s];
  }
}

// K2 v9 (R18, byte-identical): counting-sort, plain-store Dpart.
__global__ __launch_bounds__(512)
void k2_bucket(const __half* __restrict__ wh, const float* __restrict__ w_arr,
               const int* __restrict__ delay_arr,
               const float* __restrict__ W_sig, const float* __restrict__ b_sig,
               float* __restrict__ Dpart)
{
  __shared__ __align__(16) ushort sorted_h[RAYS*16];   // 16,448 B
  __shared__ float  sorted_w[RAYS];                    //  2,056 B
  __shared__ float  P[RAYS][JC+1];                     // 34,952 B
  __shared__ float  part[32][JC+1];                    //  2,176 B (posbuf alias)
  __shared__ int    hist[LSEQ];                        //  2,048 B
  __shared__ int    cum[LSEQ];                         //  2,048 B
  __shared__ int    delay_l[RAYS];                     //  2,056 B
  __shared__ float  w_l[RAYS];                         //  2,056 B
  __shared__ int    wtot[8];                           //     32 B (~63.9 KB)

  const int blk = blockIdx.x;
  const int bsid = blk / SPLIT, p = blk % SPLIT;
  const int tid = threadIdx.x;
  const int wv = tid >> 6, lane = tid & 63;
  const int obase = bsid * RAYS;
  int* posbuf = (int*)&part[0][0];                     // 514 ints fit in 2,176 B

  // phase 1: load delays/w, zero histogram
  hist[tid] = 0;
  for (int i = tid; i < RAYS; i += 512){
    delay_l[i] = delay_arr[obase + i];
    if (p == 0) w_l[i] = w_arr[obase + i];
  }
  __syncthreads();

  // phase 2: histogram (int LDS atomics, 514 lane-ops)
  for (int i = tid; i < RAYS; i += 512) atomicAdd(&hist[delay_l[i]], 1);
  __syncthreads();

  // phase 3: inclusive scan of hist -> cum; hist -> exclusive base (in place)
  int h0 = hist[tid];
  {
    int v = h0;
    #pragma unroll
    for (int m=1; m<64; m<<=1){ int u = __shfl_up(v, m, 64); if (lane >= m) v += u; }
    if (lane == 63) wtot[wv] = v;
    __syncthreads();
    int off = 0;
    for (int t=0; t<wv; t++) off += wtot[t];
    int cumv = v + off;
    cum[tid] = cumv;
    hist[tid] = cumv - h0;                 // exclusive base = rank counter seed
  }
  __syncthreads();

  // phase 4a: per-ray position (one ds_add_rtn per ray)
  for (int i = tid; i < RAYS; i += 512)
    posbuf[i] = atomicAdd(&hist[delay_l[i]], 1);
  __syncthreads();

  // phase 4b: permute wh into sorted order (coalesced global -> plain ds_write)
  {
    const uint4* whp = (const uint4*)(wh + ((size_t)p*BS*NS + bsid)*RAYS*16);
    uint4* s4 = (uint4*)sorted_h;
    for (int idx = tid; idx < RAYS*2; idx += 512){
      int r = idx >> 1, half = idx & 1;
      uint4 v = whp[idx];
      s4[posbuf[r]*2 + half] = v;
    }
    if (p == 0)
      for (int i = tid; i < RAYS; i += 512) sorted_w[posbuf[i]] = w_l[i];
  }
  __syncthreads();

  // phase 5: prefix pass 1 — 32 segs x 17 rows over sorted data -> P
  const int seg = tid >> 4, col = tid & 15;
  const int r0 = seg*17;
  const int re = max(0, min(17, RAYS - r0));
  {
    float run = 0.f;
    for (int k=0; k<re; k++){
      run += __half2float(__ushort_as_half(sorted_h[(r0+k)*16 + col]));
      P[r0+k][col] = run;
    }
    part[seg][col] = run;                  // 0 for empty segs
    if (p == 0 && col == 15){
      float rw = 0.f;
      for (int k=0; k<re; k++){ rw += sorted_w[r0+k]; P[r0+k][JC] = rw; }
      part[seg][JC] = rw;
    }
  }
  __syncthreads();

  // phase 6: pass 2 — 8 waves; wave w scans part cols w and w+8 via shfl
  if (lane < 32){
    float v1 = part[lane][wv], v2 = part[lane][wv+8];
    #pragma unroll
    for (int m=1; m<32; m<<=1){
      float u1 = __shfl_up(v1, m, 32);
      float u2 = __shfl_up(v2, m, 32);
      if (lane >= m){ v1 += u1; v2 += u2; }
    }
    part[lane][wv] = v1; part[lane][wv+8] = v2;
    if (wv == 7 && p == 0){
      float vw = part[lane][JC];
      #pragma unroll
      for (int m=1; m<32; m<<=1){
        float uw = __shfl_up(vw, m, 32);
        if (lane >= m) vw += uw;
      }
      part[lane][JC] = vw;
    }
  }
  __syncthreads();

  // phase 7: pass 3 — add exclusive segment offsets back
  {
    float off = (seg > 0) ? part[seg-1][col] : 0.f;
    for (int k=0; k<re; k++) P[r0+k][col] += off;
    if (p == 0 && col == 15){
      float ow = (seg > 0) ? part[seg-1][JC] : 0.f;
      for (int k=0; k<re; k++) P[r0+k][JC] += ow;
    }
  }
  __syncthreads();

  // phase 8: dot + mask + path loss -> PLAIN store into Dpart[p][bsid][l]
  const int s = bsid % NS;
  const float dv = dval(s);
  const float shiftf = rintf((16000.0f*dv)/343.0f);
  const int shift = (int)shiftf;
  const int jbase = p*JC;
  {
    const int l = tid;
    float mt = (((float)(LSEQ-1-l)) - shiftf > 0.f) ? 1.f : 0.f;
    const int c = cum[l];                  // # rays with delay <= l
    float val = 0.f;
    if (mt > 0.f && c > 0){
      const int row = c - 1;
      float acc = 0.f;
      #pragma unroll
      for (int jj=0;jj<JC;jj++) acc += P[row][jj] * W_sig[(jbase+jj)*LSEQ + l];
      if (p == 0) acc += b_sig[l] * P[row][JC];
      int pli = shift + l;
      if (pli < 4) pli = 5;                // path_loss[:4] = path_loss[5]
      float ideal = ((float)pli/16000.0f)*343.0f;
      val = acc / (ideal + 0.001f);
    }
    Dpart[((size_t)p*BS*NS + bsid)*LSEQ + l] = val;
  }
}

// K3 (R18, byte-identical): cubic-factorized register-twiddle DFT; gs4 load
// sums the 4 Dpart partials (linearity — exact).
__global__ __launch_bounds__(256)
void k3_dft(const float* __restrict__ Dpart, float* __restrict__ out)
{
  __shared__ float4 gs4[LSEQ/4];
  __shared__ float red[4][64][2];
  const int blk = blockIdx.x;
  const int bsid = blk >> 2, grp = blk & 3;
  const int b = bsid / NS, s = bsid % NS;
  const int tid = threadIdx.x;
  const int c = tid >> 6, bl = tid & 63;         // c = l-chunk wave, bl = bin

  if (tid < LSEQ/4){
    const float4* d0 = (const float4*)(Dpart + ((size_t)0*BS*NS + bsid)*LSEQ);
    const float4* d1 = (const float4*)(Dpart + ((size_t)1*BS*NS + bsid)*LSEQ);
    const float4* d2 = (const float4*)(Dpart + ((size_t)2*BS*NS + bsid)*LSEQ);
    const float4* d3 = (const float4*)(Dpart + ((size_t)3*BS*NS + bsid)*LSEQ);
    float4 a0 = d0[tid], a1 = d1[tid], a2 = d2[tid], a3 = d3[tid];
    gs4[tid] = make_float4(a0.x+a1.x+a2.x+a3.x, a0.y+a1.y+a2.y+a3.y,
                           a0.z+a1.z+a2.z+a3.z, a0.w+a1.w+a2.w+a3.w);
  }
  __syncthreads();

  const int k = grp*64 + bl;
  float re = 0.f, im = 0.f;
  {
    float s1, c1; sincosf(-(TWO_PI_F/512.0f)*(float)k, &s1, &c1);
    float c2 = c1*c1 - s1*s1,  s2 = 2.0f*c1*s1;
    float c3 = c1*c2 - s1*s2,  s3 = c1*s2 + s1*c2;
    float c4 = c2*c2 - s2*s2,  s4 = 2.0f*c2*s2;
    const int l0 = c*128;
    int t0 = (k*l0) & (LSEQ-1);
    float wi, wr; sincosf(-(TWO_PI_F/512.0f)*(float)t0, &wi, &wr);
    for (int q=0; q<32; q++){
      float4 gv = gs4[c*32 + q];                 // wave-uniform broadcast
      float pr = gv.x + gv.y*c1 + gv.z*c2 + gv.w*c3;
      float pi =        gv.y*s1 + gv.z*s2 + gv.w*s3;
      re = fmaf(pr, wr, re); re = fmaf(-pi, wi, re);
      im = fmaf(pr, wi, im); im = fmaf( pi, wr, im);
      float nr = wr*c4 - wi*s4;
      wi = fmaf(wr, s4, wi*c4);
      wr = nr;
    }
  }
  red[c][bl][0] = re; red[c][bl][1] = im;
  __syncthreads();

  const float cfrac = (16000.0f*dval(s))/343.0f; // fractional pts2rx_idx
  if (tid < 64){
    const int kk = grp*64 + tid;
    float rs = red[0][tid][0] + red[1][tid][0] + red[2][tid][0] + red[3][tid][0];
    float is = red[0][tid][1] + red[1][tid][1] + red[2][tid][1] + red[3][tid][1];
    float ang = -(TWO_PI_F/512.0f)*((float)kk*cfrac);
    float sp, cp; sincosf(ang, &sp, &cp);
    atomicAdd(&out[(b*NF + kk)*2],     rs*cp - is*sp);
    atomicAdd(&out[(b*NF + kk)*2 + 1], rs*sp + is*cp);
  } else if (grp == 0 && tid < 128){
    int t = tid - 64;
    float4 a = gs4[t], bq = gs4[t+64];
    float alt = (a.x - a.y + a.z - a.w) + (bq.x - bq.y + bq.z - bq.w);
    #pragma unroll
    for (int m=32; m>=1; m>>=1) alt += __shfl_xor(alt, m, 64);
    if (t == 0){
      float ang = -(TWO_PI_F/512.0f)*(256.0f*cfrac);
      float sp, cp; sincosf(ang, &sp, &cp);
      atomicAdd(&out[(b*NF + 256)*2],     alt*cp);
      atomicAdd(&out[(b*NF + 256)*2 + 1], alt*sp);
    }
  }
}

extern "C" void kernel_launch(void* const* d_in, const int* in_sizes, int n_in,
                              void* d_out, int out_size, void* d_ws, size_t ws_size,
                              hipStream_t stream)
{
  const float* rays_o      = (const float*)d_in[0];
  const float* position_tx = (const float*)d_in[1];
  const float* W1          = (const float*)d_in[2];
  const float* b1          = (const float*)d_in[3];
  const float* w_attn      = (const float*)d_in[4];
  const float* W_sig       = (const float*)d_in[5];
  const float* b_sig       = (const float*)d_in[6];
  float* out = (float*)d_out;

  // workspace layout (~10.0 MB total)
  char* ws = (char*)d_ws;
  __half* wh       = (__half*)ws;                               // 4*128*514*16*2B = 8,421,376
  float* w_arr     = (float*)(ws + 8421376);                    // 263,168
  int*   delay_arr = (int*)  (ws + 8421376 + 263168);           // 263,168
  float* Dpart     = (float*)(ws + 8421376 + 2*263168);         // 4*128*512*4 = 1,048,576

  k1_rays  <<<(BS*RAYS)/4, 1024, 0, stream>>>(rays_o, position_tx, W1, b1, w_attn,
                                              wh, w_arr, delay_arr, out);
  k2_bucket<<<BS*NS*SPLIT,  512, 0, stream>>>(wh, w_arr, delay_arr, W_sig, b_sig, Dpart);
  k3_dft   <<<BS*NS*4,      256, 0, stream>>>(Dpart, out);
}

// Round 23
// 32.602 us; speedup vs baseline: 1.2338x; 1.2338x over previous
//
#include <hip/hip_runtime.h>
#include <hip/hip_fp16.h>
#include <stdint.h>
#include <math.h>

#define BS    2
#define RAYS  514
#define NS    64
#define LSEQ  512
#define NF    257
#define HIDN  64
#define SPLIT 4
#define JC    16      // hidden columns per k2 block

#define TWO_PI_F 6.28318530717958647692f

__device__ __forceinline__ uint32_t rotl32(uint32_t x, int d){ return (x<<d)|(x>>(32-d)); }

__device__ __forceinline__ void tf_rounds4(uint32_t& x0, uint32_t& x1, int a, int b, int c, int d){
  x0+=x1; x1=rotl32(x1,a); x1^=x0;
  x0+=x1; x1=rotl32(x1,b); x1^=x0;
  x0+=x1; x1=rotl32(x1,c); x1^=x0;
  x0+=x1; x1=rotl32(x1,d); x1^=x0;
}

// Threefry-2x32, 20 rounds, matching jax._src.prng.threefry2x32
__device__ void threefry2x32(uint32_t k0, uint32_t k1, uint32_t x0, uint32_t x1,
                             uint32_t& o0, uint32_t& o1)
{
  const uint32_t ks2 = k0 ^ k1 ^ 0x1BD11BDAu;
  x0 += k0; x1 += k1;
  tf_rounds4(x0,x1,13,15,26,6);   x0+=k1;  x1+=ks2+1u;
  tf_rounds4(x0,x1,17,29,16,24);  x0+=ks2; x1+=k0+2u;
  tf_rounds4(x0,x1,13,15,26,6);   x0+=k0;  x1+=k1+3u;
  tf_rounds4(x0,x1,17,29,16,24);  x0+=k1;  x1+=ks2+4u;
  tf_rounds4(x0,x1,13,15,26,6);   x0+=ks2; x1+=k0+5u;
  o0 = x0; o1 = x1;
}

// Reproduces _ray_directions() for ray r (verified round 0).
__device__ void ray_dir(int r, float d[3])
{
  if (r >= 512) { d[0]=0.f; d[1]=0.f; d[2] = (r==512) ? 1.0f : -1.0f; return; }
  int i = r >> 4, j = r & 15;
  uint32_t o0, o1;
  threefry2x32(0u, 42u, 0u, (uint32_t)i, o0, o1);
  uint32_t bits = o0 ^ o1;
  float u = __uint_as_float((bits >> 9) | 0x3F800000u) - 1.0f;   // uniform [0,1)
  const float step = TWO_PI_F / 32.0f;
  float a = (float)i * step + step * u;
  float e = acosf(2.0f * ((float)(j+1) * (1.0f/17.0f)) - 1.0f);
  float se = sinf(e);
  d[0] = cosf(a) * se;
  d[1] = sinf(a) * se;
  d[2] = cosf(e);
}

__device__ __forceinline__ float dval(int s){ return ((float)s*(1.0f/63.0f))*7.9f + 0.1f; }

__device__ __forceinline__ uint32_t pk2(float a, float b){
  return (uint32_t)__half_as_ushort(__float2half(a)) |
         ((uint32_t)__half_as_ushort(__float2half(b)) << 16);
}

// K1 v5b: R20 shape (4 waves/block, wave = one (b,r), lane = s; LDS-tile +
// 128-B-chunk cooperative writeout) + LDS-staged weights. R22's staging bug
// fixed: grid-stride loop covers all 576 W1 floats with 256 threads; tids
// 0-63 stage b1, 64-127 stage w_attn.
__global__ __launch_bounds__(256)
void k1_rays(const float* __restrict__ rays_o, const float* __restrict__ position_tx,
             const float* __restrict__ W1, const float* __restrict__ b1,
             const float* __restrict__ w_attn,
             __half* __restrict__ wh, float* __restrict__ w_arr, int* __restrict__ delay_arr,
             float* __restrict__ out)
{
  __shared__ uint4 tile[8][4][64];   // [p*2+half][r_local][s] = 32,768 B
  __shared__ float ws1[9*HIDN];      // 2,304 B
  __shared__ float wb1[HIDN];        //   256 B
  __shared__ float wat[HIDN];        //   256 B  (total ~35.6 KB)
  const int tid = threadIdx.x;
  const int wid = tid >> 6, lane = tid & 63;       // lane = s index
  const int br = blockIdx.x*4 + wid;               // 257*4 = 1028 = BS*RAYS
  const int b = br / RAYS, r = br % RAYS;

  { // stage weights into LDS (FIXED: full coverage with 256 threads)
    for (int i = tid; i < 9*HIDN; i += 256) ws1[i] = W1[i];
    if (tid < HIDN) wb1[tid] = b1[tid];
    else if (tid < 2*HIDN) wat[tid - HIDN] = w_attn[tid - HIDN];
  }
  { // zero the atomic output accumulator
    int gi = blockIdx.x*256 + tid;
    if (gi < BS*NF*2) out[gi] = 0.f;
  }

  float dir[3]; ray_dir(r, dir);
  const float mn[3] = {-5.f,-5.f,-3.f}, mx[3] = {5.f,5.f,3.f};
  float ro[3], ntx[3];
  #pragma unroll
  for (int c=0;c<3;c++){
    ro[c] = rays_o[b*3+c];
    float t = position_tx[b*3+c];
    ntx[c] = 2.0f*(t - mn[c])/(mx[c]-mn[c]) - 1.0f;
  }

  const float dv = dval(lane);
  float feat[9], dd2 = 0.f;
  #pragma unroll
  for (int c=0;c<3;c++){
    float pt = ro[c] + dir[c]*dv;
    float npt = 2.0f*(pt - mn[c])/(mx[c]-mn[c]) - 1.0f;
    float ddc = ((ntx[c]-npt) + 1.0f)/2.0f*(mx[c]-mn[c]) + mn[c];
    dd2 += ddc*ddc;
    feat[c]   = npt;
    feat[3+c] = -dir[c];
    feat[6+c] = ntx[c];
  }
  __syncthreads();   // weights staged

  float h[HIDN];
  float av = 0.f;
  #pragma unroll
  for (int j=0; j<HIDN; j++){
    float hj = wb1[j];
    #pragma unroll
    for (int f=0; f<9; f++) hj = fmaf(feat[f], ws1[f*HIDN + j], hj);
    hj = fmaxf(hj, 0.0f);
    h[j] = hj;
    av = fmaf(hj, wat[j], av);
  }

  float attn = fmaxf(av, 0.f) + log1pf(expf(-fabsf(av)));   // softplus
  float dist = (lane < NS-1) ? (dval(lane+1) - dv) : 1e10f;
  float alpha = 1.0f - expf(-attn*dist);

  // inclusive multiplicative scan of (1-alpha+1e-6), shifted -> transmittance
  float fac = 1.0f - alpha + 1e-6f;
  float scan = fac;
  #pragma unroll
  for (int m=1; m<64; m<<=1){
    float up = __shfl_up(scan, m, 64);
    if (lane >= m) scan *= up;
  }
  float T = __shfl_up(scan, 1, 64);
  if (lane == 0) T = 1.0f;
  float wgt = T * alpha;

  float delf = fminf(fmaxf(rintf(sqrtf(dd2)*16000.0f/343.0f), 0.f), 511.f);

  const int bsid = b*NS + lane;
  const int o2 = bsid*RAYS + r;
  w_arr[o2] = wgt;
  delay_arr[o2] = (int)delf;

  // stage this lane's 4 p-quarters (8 uint4) into the LDS tile
  #pragma unroll
  for (int p=0; p<SPLIT; p++){
    uint4 v0, v1;
    v0.x = pk2(wgt*h[p*16+ 0], wgt*h[p*16+ 1]);
    v0.y = pk2(wgt*h[p*16+ 2], wgt*h[p*16+ 3]);
    v0.z = pk2(wgt*h[p*16+ 4], wgt*h[p*16+ 5]);
    v0.w = pk2(wgt*h[p*16+ 6], wgt*h[p*16+ 7]);
    v1.x = pk2(wgt*h[p*16+ 8], wgt*h[p*16+ 9]);
    v1.y = pk2(wgt*h[p*16+10], wgt*h[p*16+11]);
    v1.z = pk2(wgt*h[p*16+12], wgt*h[p*16+13]);
    v1.w = pk2(wgt*h[p*16+14], wgt*h[p*16+15]);
    tile[p*2+0][wid][lane] = v0;
    tile[p*2+1][wid][lane] = v1;
  }
  __syncthreads();

  // cooperative write-out: 2048 uint4s in 8 sweeps; 8 consecutive tids cover
  // one contiguous 128-B destination chunk (4 r_local x 2 half, fixed (p,s)).
  uint4* wh4 = (uint4*)wh;
  #pragma unroll
  for (int i=0; i<8; i++){
    int g = i*256 + tid;
    int slot = g & 7, s = (g >> 3) & 63, p = g >> 9;
    int rl = slot >> 1, half = slot & 1;
    int brl = blockIdx.x*4 + rl;
    int bb = brl / RAYS, rr = brl - bb*RAYS;
    size_t idx4 = (((size_t)p*BS*NS + bb*NS + s)*RAYS + rr)*2 + half;
    wh4[idx4] = tile[p*2+half][rl][s];
  }
}

// K2 v9 (R18, byte-identical): counting-sort, plain-store Dpart.
__global__ __launch_bounds__(512)
void k2_bucket(const __half* __restrict__ wh, const float* __restrict__ w_arr,
               const int* __restrict__ delay_arr,
               const float* __restrict__ W_sig, const float* __restrict__ b_sig,
               float* __restrict__ Dpart)
{
  __shared__ __align__(16) ushort sorted_h[RAYS*16];   // 16,448 B
  __shared__ float  sorted_w[RAYS];                    //  2,056 B
  __shared__ float  P[RAYS][JC+1];                     // 34,952 B
  __shared__ float  part[32][JC+1];                    //  2,176 B (posbuf alias)
  __shared__ int    hist[LSEQ];                        //  2,048 B
  __shared__ int    cum[LSEQ];                         //  2,048 B
  __shared__ int    delay_l[RAYS];                     //  2,056 B
  __shared__ float  w_l[RAYS];                         //  2,056 B
  __shared__ int    wtot[8];                           //     32 B (~63.9 KB)

  const int blk = blockIdx.x;
  const int bsid = blk / SPLIT, p = blk % SPLIT;
  const int tid = threadIdx.x;
  const int wv = tid >> 6, lane = tid & 63;
  const int obase = bsid * RAYS;
  int* posbuf = (int*)&part[0][0];                     // 514 ints fit in 2,176 B

  // phase 1: load delays/w, zero histogram
  hist[tid] = 0;
  for (int i = tid; i < RAYS; i += 512){
    delay_l[i] = delay_arr[obase + i];
    if (p == 0) w_l[i] = w_arr[obase + i];
  }
  __syncthreads();

  // phase 2: histogram (int LDS atomics, 514 lane-ops)
  for (int i = tid; i < RAYS; i += 512) atomicAdd(&hist[delay_l[i]], 1);
  __syncthreads();

  // phase 3: inclusive scan of hist -> cum; hist -> exclusive base (in place)
  int h0 = hist[tid];
  {
    int v = h0;
    #pragma unroll
    for (int m=1; m<64; m<<=1){ int u = __shfl_up(v, m, 64); if (lane >= m) v += u; }
    if (lane == 63) wtot[wv] = v;
    __syncthreads();
    int off = 0;
    for (int t=0; t<wv; t++) off += wtot[t];
    int cumv = v + off;
    cum[tid] = cumv;
    hist[tid] = cumv - h0;                 // exclusive base = rank counter seed
  }
  __syncthreads();

  // phase 4a: per-ray position (one ds_add_rtn per ray)
  for (int i = tid; i < RAYS; i += 512)
    posbuf[i] = atomicAdd(&hist[delay_l[i]], 1);
  __syncthreads();

  // phase 4b: permute wh into sorted order (coalesced global -> plain ds_write)
  {
    const uint4* whp = (const uint4*)(wh + ((size_t)p*BS*NS + bsid)*RAYS*16);
    uint4* s4 = (uint4*)sorted_h;
    for (int idx = tid; idx < RAYS*2; idx += 512){
      int r = idx >> 1, half = idx & 1;
      uint4 v = whp[idx];
      s4[posbuf[r]*2 + half] = v;
    }
    if (p == 0)
      for (int i = tid; i < RAYS; i += 512) sorted_w[posbuf[i]] = w_l[i];
  }
  __syncthreads();

  // phase 5: prefix pass 1 — 32 segs x 17 rows over sorted data -> P
  const int seg = tid >> 4, col = tid & 15;
  const int r0 = seg*17;
  const int re = max(0, min(17, RAYS - r0));
  {
    float run = 0.f;
    for (int k=0; k<re; k++){
      run += __half2float(__ushort_as_half(sorted_h[(r0+k)*16 + col]));
      P[r0+k][col] = run;
    }
    part[seg][col] = run;                  // 0 for empty segs
    if (p == 0 && col == 15){
      float rw = 0.f;
      for (int k=0; k<re; k++){ rw += sorted_w[r0+k]; P[r0+k][JC] = rw; }
      part[seg][JC] = rw;
    }
  }
  __syncthreads();

  // phase 6: pass 2 — 8 waves; wave w scans part cols w and w+8 via shfl
  if (lane < 32){
    float v1 = part[lane][wv], v2 = part[lane][wv+8];
    #pragma unroll
    for (int m=1; m<32; m<<=1){
      float u1 = __shfl_up(v1, m, 32);
      float u2 = __shfl_up(v2, m, 32);
      if (lane >= m){ v1 += u1; v2 += u2; }
    }
    part[lane][wv] = v1; part[lane][wv+8] = v2;
    if (wv == 7 && p == 0){
      float vw = part[lane][JC];
      #pragma unroll
      for (int m=1; m<32; m<<=1){
        float uw = __shfl_up(vw, m, 32);
        if (lane >= m) vw += uw;
      }
      part[lane][JC] = vw;
    }
  }
  __syncthreads();

  // phase 7: pass 3 — add exclusive segment offsets back
  {
    float off = (seg > 0) ? part[seg-1][col] : 0.f;
    for (int k=0; k<re; k++) P[r0+k][col] += off;
    if (p == 0 && col == 15){
      float ow = (seg > 0) ? part[seg-1][JC] : 0.f;
      for (int k=0; k<re; k++) P[r0+k][JC] += ow;
    }
  }
  __syncthreads();

  // phase 8: dot + mask + path loss -> PLAIN store into Dpart[p][bsid][l]
  const int s = bsid % NS;
  const float dv = dval(s);
  const float shiftf = rintf((16000.0f*dv)/343.0f);
  const int shift = (int)shiftf;
  const int jbase = p*JC;
  {
    const int l = tid;
    float mt = (((float)(LSEQ-1-l)) - shiftf > 0.f) ? 1.f : 0.f;
    const int c = cum[l];                  // # rays with delay <= l
    float val = 0.f;
    if (mt > 0.f && c > 0){
      const int row = c - 1;
      float acc = 0.f;
      #pragma unroll
      for (int jj=0;jj<JC;jj++) acc += P[row][jj] * W_sig[(jbase+jj)*LSEQ + l];
      if (p == 0) acc += b_sig[l] * P[row][JC];
      int pli = shift + l;
      if (pli < 4) pli = 5;                // path_loss[:4] = path_loss[5]
      float ideal = ((float)pli/16000.0f)*343.0f;
      val = acc / (ideal + 0.001f);
    }
    Dpart[((size_t)p*BS*NS + bsid)*LSEQ + l] = val;
  }
}

// K3 (R18, byte-identical): cubic-factorized register-twiddle DFT; gs4 load
// sums the 4 Dpart partials (linearity — exact).
__global__ __launch_bounds__(256)
void k3_dft(const float* __restrict__ Dpart, float* __restrict__ out)
{
  __shared__ float4 gs4[LSEQ/4];
  __shared__ float red[4][64][2];
  const int blk = blockIdx.x;
  const int bsid = blk >> 2, grp = blk & 3;
  const int b = bsid / NS, s = bsid % NS;
  const int tid = threadIdx.x;
  const int c = tid >> 6, bl = tid & 63;         // c = l-chunk wave, bl = bin

  if (tid < LSEQ/4){
    const float4* d0 = (const float4*)(Dpart + ((size_t)0*BS*NS + bsid)*LSEQ);
    const float4* d1 = (const float4*)(Dpart + ((size_t)1*BS*NS + bsid)*LSEQ);
    const float4* d2 = (const float4*)(Dpart + ((size_t)2*BS*NS + bsid)*LSEQ);
    const float4* d3 = (const float4*)(Dpart + ((size_t)3*BS*NS + bsid)*LSEQ);
    float4 a0 = d0[tid], a1 = d1[tid], a2 = d2[tid], a3 = d3[tid];
    gs4[tid] = make_float4(a0.x+a1.x+a2.x+a3.x, a0.y+a1.y+a2.y+a3.y,
                           a0.z+a1.z+a2.z+a3.z, a0.w+a1.w+a2.w+a3.w);
  }
  __syncthreads();

  const int k = grp*64 + bl;
  float re = 0.f, im = 0.f;
  {
    float s1, c1; sincosf(-(TWO_PI_F/512.0f)*(float)k, &s1, &c1);
    float c2 = c1*c1 - s1*s1,  s2 = 2.0f*c1*s1;
    float c3 = c1*c2 - s1*s2,  s3 = c1*s2 + s1*c2;
    float c4 = c2*c2 - s2*s2,  s4 = 2.0f*c2*s2;
    const int l0 = c*128;
    int t0 = (k*l0) & (LSEQ-1);
    float wi, wr; sincosf(-(TWO_PI_F/512.0f)*(float)t0, &wi, &wr);
    for (int q=0; q<32; q++){
      float4 gv = gs4[c*32 + q];                 // wave-uniform broadcast
      float pr = gv.x + gv.y*c1 + gv.z*c2 + gv.w*c3;
      float pi =        gv.y*s1 + gv.z*s2 + gv.w*s3;
      re = fmaf(pr, wr, re); re = fmaf(-pi, wi, re);
      im = fmaf(pr, wi, im); im = fmaf( pi, wr, im);
      float nr = wr*c4 - wi*s4;
      wi = fmaf(wr, s4, wi*c4);
      wr = nr;
    }
  }
  red[c][bl][0] = re; red[c][bl][1] = im;
  __syncthreads();

  const float cfrac = (16000.0f*dval(s))/343.0f; // fractional pts2rx_idx
  if (tid < 64){
    const int kk = grp*64 + tid;
    float rs = red[0][tid][0] + red[1][tid][0] + red[2][tid][0] + red[3][tid][0];
    float is = red[0][tid][1] + red[1][tid][1] + red[2][tid][1] + red[3][tid][1];
    float ang = -(TWO_PI_F/512.0f)*((float)kk*cfrac);
    float sp, cp; sincosf(ang, &sp, &cp);
    atomicAdd(&out[(b*NF + kk)*2],     rs*cp - is*sp);
    atomicAdd(&out[(b*NF + kk)*2 + 1], rs*sp + is*cp);
  } else if (grp == 0 && tid < 128){
    int t = tid - 64;
    float4 a = gs4[t], bq = gs4[t+64];
    float alt = (a.x - a.y + a.z - a.w) + (bq.x - bq.y + bq.z - bq.w);
    #pragma unroll
    for (int m=32; m>=1; m>>=1) alt += __shfl_xor(alt, m, 64);
    if (t == 0){
      float ang = -(TWO_PI_F/512.0f)*(256.0f*cfrac);
      float sp, cp; sincosf(ang, &sp, &cp);
      atomicAdd(&out[(b*NF + 256)*2],     alt*cp);
      atomicAdd(&out[(b*NF + 256)*2 + 1], alt*sp);
    }
  }
}

extern "C" void kernel_launch(void* const* d_in, const int* in_sizes, int n_in,
                              void* d_out, int out_size, void* d_ws, size_t ws_size,
                              hipStream_t stream)
{
  const float* rays_o      = (const float*)d_in[0];
  const float* position_tx = (const float*)d_in[1];
  const float* W1          = (const float*)d_in[2];
  const float* b1          = (const float*)d_in[3];
  const float* w_attn      = (const float*)d_in[4];
  const float* W_sig       = (const float*)d_in[5];
  const float* b_sig       = (const float*)d_in[6];
  float* out = (float*)d_out;

  // workspace layout (~10.0 MB total)
  char* ws = (char*)d_ws;
  __half* wh       = (__half*)ws;                               // 4*128*514*16*2B = 8,421,376
  float* w_arr     = (float*)(ws + 8421376);                    // 263,168
  int*   delay_arr = (int*)  (ws + 8421376 + 263168);           // 263,168
  float* Dpart     = (float*)(ws + 8421376 + 2*263168);         // 4*128*512*4 = 1,048,576

  k1_rays  <<<(BS*RAYS)/4,  256, 0, stream>>>(rays_o, position_tx, W1, b1, w_attn,
                                              wh, w_arr, delay_arr, out);
  k2_bucket<<<BS*NS*SPLIT,  512, 0, stream>>>(wh, w_arr, delay_arr, W_sig, b_sig, Dpart);
  k3_dft   <<<BS*NS*4,      256, 0, stream>>>(Dpart, out);
}